// Round 7
// baseline (120.099 us; speedup 1.0000x reference)
//
#include <hip/hip_runtime.h>
#include <stdint.h>
#include <stddef.h>

// ---------------- constants ----------------
#define BATCH   16384
#define CDIM    13
#define NFEAT   26
#define VROWS   100000
#define EDIM    64
#define NEMB    27      // bottom + 26 embeddings
#define NINTER  351     // 27*26/2
#define TOPIN   2079    // 351 + 27*64
#define KP4     2112    // padded K for layer 4 (33 x 64)
#define BN_INVF 0.9999950000374997f

typedef __attribute__((ext_vector_type(8)))  __bf16 bf16x8;
typedef __attribute__((ext_vector_type(4)))  float  f32x4;
typedef __attribute__((ext_vector_type(16))) float  f32x16;
typedef __attribute__((ext_vector_type(4)))  uint32_t uint4v;

__device__ __forceinline__ uint32_t f2bf(float f){
  uint32_t u = __float_as_uint(f);
  return (u + 0x7fffu + ((u >> 16) & 1u)) >> 16;   // RNE
}
__device__ __forceinline__ float bf2f(uint32_t h){ return __uint_as_float(h << 16); }
__device__ __forceinline__ uint32_t pack2(float a, float b){
  return f2bf(a) | (f2bf(b) << 16);
}
__device__ __forceinline__ void async_load16(const void* g, void* l){
  __builtin_amdgcn_global_load_lds(
      (const __attribute__((address_space(1))) uint32_t*)g,
      (__attribute__((address_space(3))) uint32_t*)l, 16, 0, 0);
}
__device__ __forceinline__ int rswz(int row){ return ((row ^ (row >> 3)) & 7) << 3; }

// ---------------- prep: all weight transposes + x hi/lo split (one launch) ----
__device__ __forceinline__ void transpose_tile(
    float (*tile)[65], const float* __restrict__ src, unsigned short* __restrict__ dst,
    int K, int N, int Kpad, int remap, int kb, int nb){
  int k0 = kb*64, n0 = nb*64, t = threadIdx.x;
  int srcBase = remap ? ((k0 < 1728) ? (k0 + 351) : (k0 - 1728)) : k0;
  #pragma unroll 4
  for(int p = 0; p < 16; p++){
    int kr = p*4 + (t >> 6), nc = t & 63;
    float v = 0.f;
    if(k0 + kr < K && (n0 + nc) < N) v = src[(size_t)(srcBase + kr) * N + n0 + nc];
    tile[kr][nc] = v;
  }
  __syncthreads();
  #pragma unroll 4
  for(int p = 0; p < 16; p++){
    int nr = p*4 + (t >> 6), kc = t & 63;
    if(k0 + kc < Kpad && (n0 + nr) < N)
      dst[(size_t)(n0 + nr) * Kpad + k0 + kc] = (unsigned short)f2bf(tile[kc][nr]);
  }
}

__global__ __launch_bounds__(256) void prep(
    const float* __restrict__ cont,
    const float* __restrict__ W1, const float* __restrict__ W2, const float* __restrict__ W3,
    const float* __restrict__ W4, const float* __restrict__ W5, const float* __restrict__ W6,
    unsigned short* __restrict__ xphi, unsigned short* __restrict__ xplo,
    unsigned short* __restrict__ W1t, unsigned short* __restrict__ W2t,
    unsigned short* __restrict__ W3t, unsigned short* __restrict__ W4t,
    unsigned short* __restrict__ W5t, unsigned short* __restrict__ W6t){
  __shared__ float tile[64][65];
  int bid = blockIdx.x;
  if(bid < 264){ transpose_tile(tile, W4, W4t, TOPIN, 512, KP4, 1, bid % 33, bid / 33); }
  else if(bid < 296){ int r = bid-264; transpose_tile(tile, W5, W5t, 512, 256, 512, 0, r % 8, r / 8); }
  else if(bid < 304){ int r = bid-296; transpose_tile(tile, W6, W6t, 256, 128, 256, 0, r % 4, r / 4); }
  else if(bid < 312){ int r = bid-304; transpose_tile(tile, W2, W2t, 256, 128, 256, 0, r % 4, r / 4); }
  else if(bid < 314){ int r = bid-312; transpose_tile(tile, W3, W3t, 128, 64, 128, 0, r, 0); }
  else if(bid < 318){ int r = bid-314; transpose_tile(tile, W1, W1t, CDIM, 256, 32, 0, 0, r); }
  else {
    // x -> hi/lo bf16, padded 13 -> 32
    int row = (bid - 318) * 256 + threadIdx.x;
    const float* xr = cont + (size_t)row * CDIM;
    uint32_t uh[16], ul[16];
    #pragma unroll
    for(int k = 0; k < 16; k++){
      uint32_t h0=0, h1=0, l0=0, l1=0;
      if(2*k < CDIM){
        float x = xr[2*k]; h0 = f2bf(x); l0 = f2bf(x - bf2f(h0));
      }
      if(2*k+1 < CDIM){
        float x = xr[2*k+1]; h1 = f2bf(x); l1 = f2bf(x - bf2f(h1));
      }
      uh[k] = h0 | (h1 << 16);
      ul[k] = l0 | (l1 << 16);
    }
    #pragma unroll
    for(int s = 0; s < 4; s++){
      uint4v vh, vl;
      #pragma unroll
      for(int e = 0; e < 4; e++){ vh[e] = uh[4*s+e]; vl[e] = ul[4*s+e]; }
      *(uint4v*)(xphi + (size_t)row*32 + s*8) = vh;
      *(uint4v*)(xplo + (size_t)row*32 + s*8) = vl;
    }
  }
}

// ---------------- bottom MLP via MFMA, hi/lo-compensated activations ----------
__global__ __launch_bounds__(256) void bottom_mfma(
    const unsigned short* __restrict__ xphi, const unsigned short* __restrict__ xplo,
    const unsigned short* __restrict__ W1t, const unsigned short* __restrict__ W2t,
    const unsigned short* __restrict__ W3t,
    const float* __restrict__ b1, const float* __restrict__ g1, const float* __restrict__ be1,
    const float* __restrict__ b2, const float* __restrict__ g2, const float* __restrict__ be2,
    const float* __restrict__ b3,
    unsigned short* __restrict__ bottomBF){
  __shared__ unsigned short h1hi[64*256];
  __shared__ unsigned short h1lo[64*256];
  __shared__ unsigned short h2hi[64*128];
  __shared__ unsigned short h2lo[64*128];
  int t = threadIdx.x, w = t >> 6, l = t & 63;
  int m0 = blockIdx.x * 64;
  int lr = l & 15, lk = (l >> 4) * 8;

  { // layer 1: M=64, N=256, K=32
    bf16x8 axh[4], axl[4];
    #pragma unroll
    for(int mt = 0; mt < 4; mt++){
      size_t ro = (size_t)(m0 + mt*16 + lr) * 32 + lk;
      axh[mt] = *(const bf16x8*)(xphi + ro);
      axl[mt] = *(const bf16x8*)(xplo + ro);
    }
    #pragma unroll
    for(int nt = 0; nt < 4; nt++){
      int n = (w*4 + nt)*16 + lr;
      bf16x8 bw = *(const bf16x8*)(W1t + (size_t)n*32 + lk);
      f32x4 acc[4];
      #pragma unroll
      for(int mt = 0; mt < 4; mt++){
        #pragma unroll
        for(int e = 0; e < 4; e++) acc[mt][e] = 0.f;
        acc[mt] = __builtin_amdgcn_mfma_f32_16x16x32_bf16(axh[mt], bw, acc[mt], 0, 0, 0);
        acc[mt] = __builtin_amdgcn_mfma_f32_16x16x32_bf16(axl[mt], bw, acc[mt], 0, 0, 0);
      }
      float sc = g1[n]*BN_INVF, bo = be1[n], bi = b1[n];
      #pragma unroll
      for(int mt = 0; mt < 4; mt++){
        #pragma unroll
        for(int q = 0; q < 4; q++){
          int row = mt*16 + (l >> 4)*4 + q;
          float y = fmaxf(sc*(acc[mt][q] + bi) + bo, 0.f);
          uint32_t hb = f2bf(y);
          int idx = row*256 + (n ^ rswz(row));
          h1hi[idx] = (unsigned short)hb;
          h1lo[idx] = (unsigned short)f2bf(y - bf2f(hb));
        }
      }
    }
  }
  __syncthreads();

  { // layer 2: M=64, N=128, K=256
    f32x4 acc[4][2];
    #pragma unroll
    for(int mt = 0; mt < 4; mt++)
      #pragma unroll
      for(int nt = 0; nt < 2; nt++)
        #pragma unroll
        for(int e = 0; e < 4; e++) acc[mt][nt][e] = 0.f;
    for(int ks = 0; ks < 8; ks++){
      bf16x8 bw[2];
      #pragma unroll
      for(int nt = 0; nt < 2; nt++){
        int n = (w*2 + nt)*16 + lr;
        bw[nt] = *(const bf16x8*)(W2t + (size_t)n*256 + ks*32 + lk);
      }
      #pragma unroll
      for(int mt = 0; mt < 4; mt++){
        int row = mt*16 + lr;
        int idx = row*256 + ((ks*32 + lk) ^ rswz(row));
        bf16x8 ah = *(const bf16x8*)(h1hi + idx);
        bf16x8 al = *(const bf16x8*)(h1lo + idx);
        #pragma unroll
        for(int nt = 0; nt < 2; nt++){
          acc[mt][nt] = __builtin_amdgcn_mfma_f32_16x16x32_bf16(ah, bw[nt], acc[mt][nt], 0, 0, 0);
          acc[mt][nt] = __builtin_amdgcn_mfma_f32_16x16x32_bf16(al, bw[nt], acc[mt][nt], 0, 0, 0);
        }
      }
    }
    #pragma unroll
    for(int nt = 0; nt < 2; nt++){
      int n = (w*2 + nt)*16 + lr;
      float sc = g2[n]*BN_INVF, bo = be2[n], bi = b2[n];
      #pragma unroll
      for(int mt = 0; mt < 4; mt++){
        #pragma unroll
        for(int q = 0; q < 4; q++){
          int row = mt*16 + (l >> 4)*4 + q;
          float y = fmaxf(sc*(acc[mt][nt][q] + bi) + bo, 0.f);
          uint32_t hb = f2bf(y);
          int idx = row*128 + (n ^ rswz(row));
          h2hi[idx] = (unsigned short)hb;
          h2lo[idx] = (unsigned short)f2bf(y - bf2f(hb));
        }
      }
    }
  }
  __syncthreads();

  { // layer 3: M=64, N=64, K=128, no BN/ReLU
    f32x4 acc[4];
    #pragma unroll
    for(int mt = 0; mt < 4; mt++)
      #pragma unroll
      for(int e = 0; e < 4; e++) acc[mt][e] = 0.f;
    int n = w*16 + lr;
    for(int ks = 0; ks < 4; ks++){
      bf16x8 bw = *(const bf16x8*)(W3t + (size_t)n*128 + ks*32 + lk);
      #pragma unroll
      for(int mt = 0; mt < 4; mt++){
        int row = mt*16 + lr;
        int idx = row*128 + ((ks*32 + lk) ^ rswz(row));
        bf16x8 ah = *(const bf16x8*)(h2hi + idx);
        bf16x8 al = *(const bf16x8*)(h2lo + idx);
        acc[mt] = __builtin_amdgcn_mfma_f32_16x16x32_bf16(ah, bw, acc[mt], 0, 0, 0);
        acc[mt] = __builtin_amdgcn_mfma_f32_16x16x32_bf16(al, bw, acc[mt], 0, 0, 0);
      }
    }
    float bi = b3[n];
    #pragma unroll
    for(int mt = 0; mt < 4; mt++){
      #pragma unroll
      for(int q = 0; q < 4; q++){
        int row = m0 + mt*16 + (l >> 4)*4 + q;
        bottomBF[(size_t)row*64 + n] = (unsigned short)f2bf(acc[mt][q] + bi);
      }
    }
  }
}

// ---------------- interact: gather + Z=E·E^T (one wave per sample) --------------
__global__ __launch_bounds__(256) void interact(
    const unsigned short* __restrict__ bottomBF, const int* __restrict__ cat_idx,
    const float* __restrict__ emb, unsigned short* __restrict__ top_in){
  __shared__ unsigned short inter_s[4][352];
  int w = threadIdx.x >> 6, l = threadIdx.x & 63;
  int b = blockIdx.x * 4 + w;
  int r = l & 31, h = l >> 5;
  bool active = (r < NEMB);
  uint4v q[4];
  if(active && r == 0){
    const unsigned short* sb = bottomBF + (size_t)b * 64;
    #pragma unroll
    for(int s = 0; s < 4; s++) q[s] = *(const uint4v*)(sb + h*8 + s*16);
  } else if(active){
    int f = r - 1;
    int idx = cat_idx[b * NFEAT + f];
    const float* src = emb + ((size_t)f * VROWS + (size_t)idx) * 64;
    #pragma unroll
    for(int s = 0; s < 4; s++){
      int k0 = h*8 + s*16;
      float4 v0 = *(const float4*)(src + k0);
      float4 v1 = *(const float4*)(src + k0 + 4);
      q[s][0] = pack2(v0.x, v0.y); q[s][1] = pack2(v0.z, v0.w);
      q[s][2] = pack2(v1.x, v1.y); q[s][3] = pack2(v1.z, v1.w);
    }
  } else {
    #pragma unroll
    for(int s = 0; s < 4; s++){ q[s][0]=0; q[s][1]=0; q[s][2]=0; q[s][3]=0; }
  }
  if(active){
    #pragma unroll
    for(int s = 0; s < 4; s++)
      *(uint4v*)(top_in + (size_t)b*KP4 + r*64 + h*8 + s*16) = q[s];
  }
  f32x16 acc;
  #pragma unroll
  for(int i = 0; i < 16; i++) acc[i] = 0.f;
  #pragma unroll
  for(int s = 0; s < 4; s++){
    bf16x8 a = __builtin_bit_cast(bf16x8, q[s]);
    acc = __builtin_amdgcn_mfma_f32_32x32x16_bf16(a, a, acc, 0, 0, 0);
  }
  if(active){
    #pragma unroll
    for(int qq = 0; qq < 16; qq++){
      int i = (qq & 3) + 8*(qq >> 2) + 4*h;
      if(i < r){
        int p = i*(53 - i)/2 + (r - i - 1);
        inter_s[w][p] = (unsigned short)f2bf(acc[qq]);
      }
    }
  }
  __syncthreads();
  size_t basei = (size_t)b*KP4 + 1728;
  for(int t0 = l; t0 < 176; t0 += 64){
    uint32_t lo = inter_s[w][2*t0];
    uint32_t hi = (2*t0 + 1 < NINTER) ? (uint32_t)inter_s[w][2*t0 + 1] : 0u;
    *(uint32_t*)(top_in + basei + 2*t0) = lo | (hi << 16);
  }
  if(l < 16) *(uint32_t*)(top_in + (size_t)b*KP4 + 2080 + 2*l) = 0;
}

// ---------------- gemm4: 256x128, 8 waves, triple-buffer, 32x32x16 frags ------
template<int KSTEPS, int NB>
__global__ __launch_bounds__(512, 2) void gemm_deep(
    const unsigned short* __restrict__ A, int sA,
    const unsigned short* __restrict__ Bw, int sB,
    const float* __restrict__ bias, const float* __restrict__ gg,
    const float* __restrict__ be,
    unsigned short* __restrict__ out, int sOut){
  __shared__ char smem[3*49152];          // 3 bufs: A 32KB + B 16KB each
  int nwg = gridDim.x;
  int bid = blockIdx.x;
  int lin = (bid & 7) * (nwg >> 3) + (bid >> 3);   // XCD chunking (nwg % 8 == 0)
  int m0 = (lin / NB) * 256, n0 = (lin % NB) * 128;
  int t = threadIdx.x, w = t >> 6, l = t & 63;
  int wr = (w >> 1) * 64, wc = (w & 1) * 64;
  int l31 = l & 31, l5 = l >> 5;
  f32x16 acc[2][2];
  #pragma unroll
  for(int i = 0; i < 2; i++)
    #pragma unroll
    for(int j = 0; j < 2; j++)
      #pragma unroll
      for(int e = 0; e < 16; e++) acc[i][j][e] = 0.f;

  const unsigned short* g[6];
  int ldsOff[6];
  #pragma unroll
  for(int i = 0; i < 6; i++){
    if(i < 4){
      int o = i*8192 + t*16;
      int row = o >> 7;
      int cb  = (o & 127) ^ ((row & 7) << 4);
      g[i] = A + (size_t)(m0 + row)*sA + (cb >> 1);
      ldsOff[i] = o;
    } else {
      int o = (i-4)*8192 + t*16;
      int row = o >> 7;
      int cb  = (o & 127) ^ ((row & 7) << 4);
      g[i] = Bw + (size_t)(n0 + row)*sB + (cb >> 1);
      ldsOff[i] = 32768 + o;
    }
  }
  int swz = (l31 & 7) << 4;               // (row&7)<<4 with row ≡ l31 mod 32

  // prologue: stage K-tiles 0 and 1
  #pragma unroll
  for(int i = 0; i < 6; i++) async_load16(g[i], smem + ldsOff[i]);
  #pragma unroll
  for(int i = 0; i < 6; i++) async_load16(g[i] + 64, smem + 49152 + ldsOff[i]);
  asm volatile("s_waitcnt vmcnt(6)" ::: "memory");
  __builtin_amdgcn_s_barrier();

  for(int kt = 0; kt < KSTEPS; kt++){
    int cur = kt % 3;
    int nxt2 = (kt + 2) % 3;
    int ksrc = (kt + 2 < KSTEPS) ? (kt + 2) : (KSTEPS - 1);  // clamped dup, never read
    const char* bA = smem + cur*49152;
    const char* bB = bA + 32768;
    #pragma unroll
    for(int ph = 0; ph < 2; ph++){
      if(ph == 0){
        #pragma unroll
        for(int i = 0; i < 3; i++)
          async_load16(g[i] + ksrc*64, smem + nxt2*49152 + ldsOff[i]);
      } else {
        #pragma unroll
        for(int i = 3; i < 6; i++)
          async_load16(g[i] + ksrc*64, smem + nxt2*49152 + ldsOff[i]);
      }
      bf16x8 af[2][2], bfr[2][2];    // [ks][mt/nt]
      #pragma unroll
      for(int ks = 0; ks < 2; ks++){
        int ko = ((ph*2 + ks)*32 + l5*16) ^ swz;
        #pragma unroll
        for(int mt = 0; mt < 2; mt++)
          af[ks][mt]  = *(const bf16x8*)(bA + (wr + mt*32 + l31)*128 + ko);
        #pragma unroll
        for(int nt = 0; nt < 2; nt++)
          bfr[ks][nt] = *(const bf16x8*)(bB + (wc + nt*32 + l31)*128 + ko);
      }
      if(ph == 1) asm volatile("s_waitcnt vmcnt(6)" ::: "memory"); // kt+1 landed
      __builtin_amdgcn_s_barrier();
      __builtin_amdgcn_s_setprio(1);
      #pragma unroll
      for(int ks = 0; ks < 2; ks++)
        #pragma unroll
        for(int mt = 0; mt < 2; mt++)
          #pragma unroll
          for(int nt = 0; nt < 2; nt++)
            acc[mt][nt] = __builtin_amdgcn_mfma_f32_32x32x16_bf16(af[ks][mt], bfr[ks][nt], acc[mt][nt], 0, 0, 0);
      __builtin_amdgcn_s_setprio(0);
      __builtin_amdgcn_s_barrier();
    }
  }

  #pragma unroll
  for(int mt = 0; mt < 2; mt++){
    #pragma unroll
    for(int nt = 0; nt < 2; nt++){
      int col = n0 + wc + nt*32 + l31;
      float sc = gg[col]*BN_INVF, bo = be[col], bi = bias[col];
      #pragma unroll
      for(int reg = 0; reg < 16; reg++){
        int rowf = (reg & 3) + 8*(reg >> 2) + 4*l5;
        int row = m0 + wr + mt*32 + rowf;
        float y = fmaxf(sc*(acc[mt][nt][reg] + bi) + bo, 0.f);
        out[(size_t)row*sOut + col] = (unsigned short)f2bf(y);
      }
    }
  }
}

// ---------------- gemm_tail: layers 5+6+7 fused, 64 rows/block, 4 waves -------
__global__ __launch_bounds__(256) void gemm_tail(
    const unsigned short* __restrict__ h4,      // [BATCH][512]
    const unsigned short* __restrict__ W5t,     // [256][512]
    const float* __restrict__ b5, const float* __restrict__ g5, const float* __restrict__ be5,
    const unsigned short* __restrict__ W6t,     // [128][256]
    const float* __restrict__ b6, const float* __restrict__ g6, const float* __restrict__ be6,
    const float* __restrict__ W7, const float* __restrict__ b7,
    float* __restrict__ scores){
  __shared__ char smem[74752];
  unsigned short* h5 = (unsigned short*)(smem + 40960);
  float* pscore = (float*)(smem + 73728);
  int t = threadIdx.x, w = t >> 6, l = t & 63;
  int m0 = blockIdx.x * 64;
  int lr = l & 15;
  int o1 = ((l >> 4) * 16) ^ ((l & 7) << 4);

  f32x4 acc5[4][4];
  #pragma unroll
  for(int i = 0; i < 4; i++)
    #pragma unroll
    for(int j = 0; j < 4; j++)
      #pragma unroll
      for(int e = 0; e < 4; e++) acc5[i][j][e] = 0.f;

  const unsigned short* gA[2]; int ldsA[2];
  #pragma unroll
  for(int i = 0; i < 2; i++){
    int o = i*4096 + t*16;
    int row = o >> 7;
    int cb = (o & 127) ^ ((row & 7) << 4);
    gA[i] = h4 + (size_t)(m0 + row)*512 + (cb >> 1);
    ldsA[i] = o;
  }
  const unsigned short* gB[8]; int ldsB[8];
  #pragma unroll
  for(int i = 0; i < 8; i++){
    int o = i*4096 + t*16;
    int row = o >> 7;
    int cb = (o & 127) ^ ((row & 7) << 4);
    gB[i] = W5t + (size_t)row*512 + (cb >> 1);
    ldsB[i] = 8192 + o;
  }

  for(int kt = 0; kt < 8; kt++){
    #pragma unroll
    for(int i = 0; i < 2; i++) async_load16(gA[i] + kt*64, smem + ldsA[i]);
    #pragma unroll
    for(int i = 0; i < 8; i++) async_load16(gB[i] + kt*64, smem + ldsB[i]);
    __syncthreads();
    #pragma unroll
    for(int ks = 0; ks < 2; ks++){
      int ko = o1 ^ (ks << 6);
      bf16x8 af[4], bfr[4];
      #pragma unroll
      for(int x = 0; x < 4; x++){
        af[x]  = *(const bf16x8*)(smem + (x*16 + lr)*128 + ko);
        bfr[x] = *(const bf16x8*)(smem + 8192 + (w*64 + x*16 + lr)*128 + ko);
      }
      #pragma unroll
      for(int tr = 0; tr < 4; tr++)
        #pragma unroll
        for(int tc = 0; tc < 4; tc++)
          acc5[tr][tc] = __builtin_amdgcn_mfma_f32_16x16x32_bf16(af[tr], bfr[tc], acc5[tr][tc], 0, 0, 0);
    }
    __syncthreads();
  }

  #pragma unroll
  for(int i = 0; i < 8; i++){
    int o = i*4096 + t*16;
    int row = o >> 8;
    int cb = (o & 255) ^ ((row & 15) << 4);
    async_load16(W6t + (size_t)row*256 + (cb >> 1), smem + o);
  }
  #pragma unroll
  for(int tc = 0; tc < 4; tc++){
    int c = w*64 + tc*16 + lr;
    float sc = g5[c]*BN_INVF, bo = be5[c], bi = b5[c];
    #pragma unroll
    for(int tr = 0; tr < 4; tr++){
      #pragma unroll
      for(int qq = 0; qq < 4; qq++){
        int row = tr*16 + (l >> 4)*4 + qq;
        float y = fmaxf(sc*(acc5[tr][tc][qq] + bi) + bo, 0.f);
        h5[row*256 + (c ^ rswz(row))] = (unsigned short)f2bf(y);
      }
    }
  }
  __syncthreads();

  f32x4 acc6[4][2];
  #pragma unroll
  for(int i = 0; i < 4; i++)
    #pragma unroll
    for(int j = 0; j < 2; j++)
      #pragma unroll
      for(int e = 0; e < 4; e++) acc6[i][j][e] = 0.f;
  int lk = (l >> 4) * 8;
  int lk2 = (l >> 4) * 16;
  #pragma unroll
  for(int half = 0; half < 2; half++){
    if(half == 1){
      __syncthreads();
      #pragma unroll
      for(int i = 0; i < 8; i++){
        int o = i*4096 + t*16;
        int row = o >> 8;
        int cb = (o & 255) ^ ((row & 15) << 4);
        async_load16(W6t + (size_t)row*256 + 128 + (cb >> 1), smem + o);
      }
      __syncthreads();
    }
    #pragma unroll
    for(int ks = 0; ks < 4; ks++){
      bf16x8 af6[4], bfr6[2];
      #pragma unroll
      for(int mt = 0; mt < 4; mt++){
        int row = mt*16 + lr;
        af6[mt] = *(const bf16x8*)(h5 + row*256 + ((half*128 + ks*32 + lk) ^ rswz(row)));
      }
      #pragma unroll
      for(int nt = 0; nt < 2; nt++){
        int row = w*32 + nt*16 + lr;
        bfr6[nt] = *(const bf16x8*)(smem + row*256 + ((ks*64 + lk2) ^ (lr << 4)));
      }
      #pragma unroll
      for(int mt = 0; mt < 4; mt++)
        #pragma unroll
        for(int nt = 0; nt < 2; nt++)
          acc6[mt][nt] = __builtin_amdgcn_mfma_f32_16x16x32_bf16(af6[mt], bfr6[nt], acc6[mt][nt], 0, 0, 0);
    }
  }

  float pr[16];
  #pragma unroll
  for(int nt = 0; nt < 2; nt++){
    int c = w*32 + nt*16 + lr;
    float sc = g6[c]*BN_INVF, bo = be6[c], bi = b6[c];
    float w7c = W7[c];
    #pragma unroll
    for(int mt = 0; mt < 4; mt++){
      #pragma unroll
      for(int qq = 0; qq < 4; qq++){
        float v = fmaxf(sc*(acc6[mt][nt][qq] + bi) + bo, 0.f) * w7c;
        if(nt == 0) pr[mt*4 + qq] = v; else pr[mt*4 + qq] += v;
      }
    }
  }
  #pragma unroll
  for(int mask = 1; mask < 16; mask <<= 1){
    #pragma unroll
    for(int i = 0; i < 16; i++) pr[i] += __shfl_xor(pr[i], mask, 64);
  }
  if(lr == 0){
    #pragma unroll
    for(int mt = 0; mt < 4; mt++)
      #pragma unroll
      for(int qq = 0; qq < 4; qq++)
        pscore[w*64 + mt*16 + (l >> 4)*4 + qq] = pr[mt*4 + qq];
  }
  __syncthreads();
  if(t < 64){
    float s = b7[0] + pscore[t] + pscore[64 + t] + pscore[128 + t] + pscore[192 + t];
    scores[m0 + t] = s;
  }
}

// ---------------- launch ----------------
static inline size_t alignup(size_t x){ return (x + 255) & ~(size_t)255; }

extern "C" void kernel_launch(void* const* d_in, const int* in_sizes, int n_in,
                              void* d_out, int out_size, void* d_ws, size_t ws_size,
                              hipStream_t stream){
  const float* cont = (const float*)d_in[0];
  const int*   cat  = (const int*)  d_in[1];
  const float* emb  = (const float*)d_in[2];
  const float* W1 = (const float*)d_in[3],  *b1 = (const float*)d_in[4];
  const float* g1 = (const float*)d_in[5],  *be1= (const float*)d_in[6];
  const float* W2 = (const float*)d_in[7],  *b2 = (const float*)d_in[8];
  const float* g2 = (const float*)d_in[9],  *be2= (const float*)d_in[10];
  const float* W3 = (const float*)d_in[11], *b3 = (const float*)d_in[12];
  const float* W4 = (const float*)d_in[13], *b4 = (const float*)d_in[14];
  const float* g4 = (const float*)d_in[15], *be4= (const float*)d_in[16];
  const float* W5 = (const float*)d_in[17], *b5 = (const float*)d_in[18];
  const float* g5 = (const float*)d_in[19], *be5= (const float*)d_in[20];
  const float* W6 = (const float*)d_in[21], *b6 = (const float*)d_in[22];
  const float* g6 = (const float*)d_in[23], *be6= (const float*)d_in[24];
  const float* W7 = (const float*)d_in[25], *b7 = (const float*)d_in[26];

  char* ws = (char*)d_ws;
  unsigned short* bottomBF = (unsigned short*)ws; ws += alignup((size_t)BATCH*64*2);
  unsigned short* xphi = (unsigned short*)ws; ws += alignup((size_t)BATCH*32*2);
  unsigned short* xplo = (unsigned short*)ws; ws += alignup((size_t)BATCH*32*2);
  unsigned short* W1t  = (unsigned short*)ws; ws += alignup((size_t)256*32*2);
  unsigned short* W2t  = (unsigned short*)ws; ws += alignup((size_t)128*256*2);
  unsigned short* W3t  = (unsigned short*)ws; ws += alignup((size_t)64*128*2);
  unsigned short* topi = (unsigned short*)ws; ws += alignup((size_t)BATCH*KP4*2);
  unsigned short* W4t  = (unsigned short*)ws; ws += alignup((size_t)512*KP4*2);
  unsigned short* W5t  = (unsigned short*)ws; ws += alignup((size_t)256*512*2);
  unsigned short* W6t  = (unsigned short*)ws; ws += alignup((size_t)128*256*2);
  unsigned short* h4   = (unsigned short*)ws; ws += alignup((size_t)BATCH*512*2);
  (void)ws_size; (void)n_in; (void)in_sizes; (void)out_size;

  hipLaunchKernelGGL(prep, dim3(382), dim3(256), 0, stream,
                     cont, W1, W2, W3, W4, W5, W6,
                     xphi, xplo, W1t, W2t, W3t, W4t, W5t, W6t);
  hipLaunchKernelGGL(bottom_mfma, dim3(BATCH/64), dim3(256), 0, stream,
                     xphi, xplo, W1t, W2t, W3t,
                     b1, g1, be1, b2, g2, be2, b3, bottomBF);
  hipLaunchKernelGGL(interact, dim3(BATCH/4), dim3(256), 0, stream, bottomBF, cat, emb, topi);
  hipLaunchKernelGGL((gemm_deep<33, 4>), dim3(256), dim3(512), 0, stream,
                     topi, KP4, W4t, KP4, b4, g4, be4, h4, 512);
  hipLaunchKernelGGL(gemm_tail, dim3(256), dim3(256), 0, stream,
                     h4, W5t, b5, g5, be5, W6t, b6, g6, be6, W7, b7, (float*)d_out);
}

// Round 8
// 116.145 us; speedup vs baseline: 1.0340x; 1.0340x over previous
//
#include <hip/hip_runtime.h>
#include <stdint.h>
#include <stddef.h>

// ---------------- constants ----------------
#define BATCH   16384
#define CDIM    13
#define NFEAT   26
#define VROWS   100000
#define EDIM    64
#define NEMB    27      // bottom + 26 embeddings
#define NINTER  351     // 27*26/2
#define TOPIN   2079    // 351 + 27*64
#define KP4     2112    // padded K for layer 4 (33 x 64)
#define BN_INVF 0.9999950000374997f

typedef __attribute__((ext_vector_type(8)))  __bf16 bf16x8;
typedef __attribute__((ext_vector_type(4)))  float  f32x4;
typedef __attribute__((ext_vector_type(16))) float  f32x16;
typedef __attribute__((ext_vector_type(4)))  uint32_t uint4v;

__device__ __forceinline__ uint32_t f2bf(float f){
  uint32_t u = __float_as_uint(f);
  return (u + 0x7fffu + ((u >> 16) & 1u)) >> 16;   // RNE
}
__device__ __forceinline__ float bf2f(uint32_t h){ return __uint_as_float(h << 16); }
__device__ __forceinline__ uint32_t pack2(float a, float b){
  return f2bf(a) | (f2bf(b) << 16);
}
__device__ __forceinline__ void async_load16(const void* g, void* l){
  __builtin_amdgcn_global_load_lds(
      (const __attribute__((address_space(1))) uint32_t*)g,
      (__attribute__((address_space(3))) uint32_t*)l, 16, 0, 0);
}
__device__ __forceinline__ int rswz(int row){ return ((row ^ (row >> 3)) & 7) << 3; }

// ---------------- prep: weight transposes only ----------------
__device__ __forceinline__ void transpose_tile(
    float (*tile)[65], const float* __restrict__ src, unsigned short* __restrict__ dst,
    int K, int N, int Kpad, int remap, int kb, int nb){
  int k0 = kb*64, n0 = nb*64, t = threadIdx.x;
  int srcBase = remap ? ((k0 < 1728) ? (k0 + 351) : (k0 - 1728)) : k0;
  #pragma unroll 4
  for(int p = 0; p < 16; p++){
    int kr = p*4 + (t >> 6), nc = t & 63;
    float v = 0.f;
    if(k0 + kr < K && (n0 + nc) < N) v = src[(size_t)(srcBase + kr) * N + n0 + nc];
    tile[kr][nc] = v;
  }
  __syncthreads();
  #pragma unroll 4
  for(int p = 0; p < 16; p++){
    int nr = p*4 + (t >> 6), kc = t & 63;
    if(k0 + kc < Kpad && (n0 + nr) < N)
      dst[(size_t)(n0 + nr) * Kpad + k0 + kc] = (unsigned short)f2bf(tile[kc][nr]);
  }
}

__global__ __launch_bounds__(256) void prep(
    const float* __restrict__ W1, const float* __restrict__ W2, const float* __restrict__ W3,
    const float* __restrict__ W4, const float* __restrict__ W5, const float* __restrict__ W6,
    unsigned short* __restrict__ W1t, unsigned short* __restrict__ W2t,
    unsigned short* __restrict__ W3t, unsigned short* __restrict__ W4t,
    unsigned short* __restrict__ W5t, unsigned short* __restrict__ W6t){
  __shared__ float tile[64][65];
  int bid = blockIdx.x;
  if(bid < 264){ transpose_tile(tile, W4, W4t, TOPIN, 512, KP4, 1, bid % 33, bid / 33); }
  else if(bid < 296){ int r = bid-264; transpose_tile(tile, W5, W5t, 512, 256, 512, 0, r % 8, r / 8); }
  else if(bid < 304){ int r = bid-296; transpose_tile(tile, W6, W6t, 256, 128, 256, 0, r % 4, r / 4); }
  else if(bid < 312){ int r = bid-304; transpose_tile(tile, W2, W2t, 256, 128, 256, 0, r % 4, r / 4); }
  else if(bid < 314){ int r = bid-312; transpose_tile(tile, W3, W3t, 128, 64, 128, 0, r, 0); }
  else               { int r = bid-314; transpose_tile(tile, W1, W1t, CDIM, 256, 32, 0, 0, r); }
}

// ---------------- fused bottom MLP + interact: 16 samples/block, 4 waves ------
// bottom: M=16 MFMA (hi/lo compensated); output in LDS.
// interact: each wave gathers+interacts 4 samples, with next-sample reg prefetch.
__global__ __launch_bounds__(256) void bottom_interact(
    const float* __restrict__ cont, const int* __restrict__ cat_idx,
    const float* __restrict__ emb,
    const unsigned short* __restrict__ W1t, const unsigned short* __restrict__ W2t,
    const unsigned short* __restrict__ W3t,
    const float* __restrict__ b1, const float* __restrict__ g1, const float* __restrict__ be1,
    const float* __restrict__ b2, const float* __restrict__ g2, const float* __restrict__ be2,
    const float* __restrict__ b3,
    unsigned short* __restrict__ top_in){
  __shared__ unsigned short h1hi[16*256];
  __shared__ unsigned short h1lo[16*256];
  __shared__ unsigned short h2hi[16*128];
  __shared__ unsigned short h2lo[16*128];
  __shared__ unsigned short bot_s[16*64];
  __shared__ unsigned short inter_s[16][352];
  int t = threadIdx.x, w = t >> 6, l = t & 63;
  int m0 = blockIdx.x * 16;
  int lr = l & 15, lg = l >> 4, lk = lg * 8;
  int r = l & 31, h = l >> 5;
  bool activeB = (r >= 1 && r < NEMB);

  // early idx loads (latency hidden under bottom phase)
  int idx4[4];
  #pragma unroll
  for(int s = 0; s < 4; s++){
    int b = m0 + w*4 + s;
    idx4[s] = activeB ? cat_idx[b*NFEAT + (r-1)] : 0;
  }

  // x A-frags straight from global: lane holds row lr, k = lk..lk+7 (hi/lo)
  bf16x8 axh, axl;
  {
    uint32_t uh[4], ul[4];
    #pragma unroll
    for(int p = 0; p < 4; p++){
      float x0 = 0.f, x1 = 0.f;
      int k0 = lk + 2*p;
      if(k0 < CDIM)     x0 = cont[(size_t)(m0 + lr)*CDIM + k0];
      if(k0 + 1 < CDIM) x1 = cont[(size_t)(m0 + lr)*CDIM + k0 + 1];
      uint32_t h0 = f2bf(x0), h1b = f2bf(x1);
      uh[p] = h0 | (h1b << 16);
      ul[p] = f2bf(x0 - bf2f(h0)) | (f2bf(x1 - bf2f(h1b)) << 16);
    }
    uint4v vh, vl;
    #pragma unroll
    for(int e = 0; e < 4; e++){ vh[e] = uh[e]; vl[e] = ul[e]; }
    axh = __builtin_bit_cast(bf16x8, vh);
    axl = __builtin_bit_cast(bf16x8, vl);
  }

  { // L1: M=16, N=256 (wave: 4 nt), K=32
    #pragma unroll
    for(int nt = 0; nt < 4; nt++){
      int n = w*64 + nt*16 + lr;
      bf16x8 bw = *(const bf16x8*)(W1t + (size_t)n*32 + lk);
      f32x4 acc;
      #pragma unroll
      for(int e = 0; e < 4; e++) acc[e] = 0.f;
      acc = __builtin_amdgcn_mfma_f32_16x16x32_bf16(axh, bw, acc, 0, 0, 0);
      acc = __builtin_amdgcn_mfma_f32_16x16x32_bf16(axl, bw, acc, 0, 0, 0);
      float sc = g1[n]*BN_INVF, bo = be1[n], bi = b1[n];
      #pragma unroll
      for(int q = 0; q < 4; q++){
        int ro = lg*4 + q;
        float y = fmaxf(sc*(acc[q] + bi) + bo, 0.f);
        uint32_t hb = f2bf(y);
        int idx = ro*256 + (n ^ rswz(ro));
        h1hi[idx] = (unsigned short)hb;
        h1lo[idx] = (unsigned short)f2bf(y - bf2f(hb));
      }
    }
  }
  __syncthreads();

  { // L2: M=16, N=128 (wave: 2 nt), K=256
    f32x4 acc[2];
    #pragma unroll
    for(int nt = 0; nt < 2; nt++)
      #pragma unroll
      for(int e = 0; e < 4; e++) acc[nt][e] = 0.f;
    for(int ks = 0; ks < 8; ks++){
      bf16x8 bw[2];
      #pragma unroll
      for(int nt = 0; nt < 2; nt++){
        int n = w*32 + nt*16 + lr;
        bw[nt] = *(const bf16x8*)(W2t + (size_t)n*256 + ks*32 + lk);
      }
      int ai = lr*256 + ((ks*32 + lk) ^ rswz(lr));
      bf16x8 ah = *(const bf16x8*)(h1hi + ai);
      bf16x8 al = *(const bf16x8*)(h1lo + ai);
      #pragma unroll
      for(int nt = 0; nt < 2; nt++){
        acc[nt] = __builtin_amdgcn_mfma_f32_16x16x32_bf16(ah, bw[nt], acc[nt], 0, 0, 0);
        acc[nt] = __builtin_amdgcn_mfma_f32_16x16x32_bf16(al, bw[nt], acc[nt], 0, 0, 0);
      }
    }
    #pragma unroll
    for(int nt = 0; nt < 2; nt++){
      int n = w*32 + nt*16 + lr;
      float sc = g2[n]*BN_INVF, bo = be2[n], bi = b2[n];
      #pragma unroll
      for(int q = 0; q < 4; q++){
        int ro = lg*4 + q;
        float y = fmaxf(sc*(acc[nt][q] + bi) + bo, 0.f);
        uint32_t hb = f2bf(y);
        int idx = ro*128 + (n ^ rswz(ro));
        h2hi[idx] = (unsigned short)hb;
        h2lo[idx] = (unsigned short)f2bf(y - bf2f(hb));
      }
    }
  }
  __syncthreads();

  { // L3: M=16, N=64 (wave: 1 nt), K=128 -> bot_s (bf16, no BN/ReLU)
    f32x4 acc;
    #pragma unroll
    for(int e = 0; e < 4; e++) acc[e] = 0.f;
    int n = w*16 + lr;
    for(int ks = 0; ks < 4; ks++){
      bf16x8 bw = *(const bf16x8*)(W3t + (size_t)n*128 + ks*32 + lk);
      int ai = lr*128 + ((ks*32 + lk) ^ rswz(lr));
      bf16x8 ah = *(const bf16x8*)(h2hi + ai);
      bf16x8 al = *(const bf16x8*)(h2lo + ai);
      acc = __builtin_amdgcn_mfma_f32_16x16x32_bf16(ah, bw, acc, 0, 0, 0);
      acc = __builtin_amdgcn_mfma_f32_16x16x32_bf16(al, bw, acc, 0, 0, 0);
    }
    float bi = b3[n];
    #pragma unroll
    for(int q = 0; q < 4; q++){
      int ro = lg*4 + q;
      bot_s[ro*64 + n] = (unsigned short)f2bf(acc[q] + bi);
    }
  }
  __syncthreads();

  // ---- interact phase: 4 samples per wave, next-sample gather prefetch ----
  float4 raw[8];
  if(activeB){
    const float* src = emb + ((size_t)(r-1)*VROWS + (size_t)idx4[0])*64;
    #pragma unroll
    for(int p = 0; p < 4; p++){
      raw[2*p]   = *(const float4*)(src + h*8 + p*16);
      raw[2*p+1] = *(const float4*)(src + h*8 + p*16 + 4);
    }
  }
  #pragma unroll
  for(int s = 0; s < 4; s++){
    int sb = w*4 + s;
    int b = m0 + sb;
    // pack current sample from raw / bot_s
    uint4v q[4];
    if(r == 0){
      #pragma unroll
      for(int p = 0; p < 4; p++)
        q[p] = *(const uint4v*)(bot_s + sb*64 + h*8 + p*16);
    } else if(activeB){
      #pragma unroll
      for(int p = 0; p < 4; p++){
        q[p][0] = pack2(raw[2*p].x, raw[2*p].y); q[p][1] = pack2(raw[2*p].z, raw[2*p].w);
        q[p][2] = pack2(raw[2*p+1].x, raw[2*p+1].y); q[p][3] = pack2(raw[2*p+1].z, raw[2*p+1].w);
      }
    } else {
      #pragma unroll
      for(int p = 0; p < 4; p++){ q[p][0]=0; q[p][1]=0; q[p][2]=0; q[p][3]=0; }
    }
    // issue next sample's gather (latency hides under MFMA + extract + stores)
    if(s < 3 && activeB){
      const float* src = emb + ((size_t)(r-1)*VROWS + (size_t)idx4[s+1])*64;
      #pragma unroll
      for(int p = 0; p < 4; p++){
        raw[2*p]   = *(const float4*)(src + h*8 + p*16);
        raw[2*p+1] = *(const float4*)(src + h*8 + p*16 + 4);
      }
    }
    if(r < NEMB){
      #pragma unroll
      for(int p = 0; p < 4; p++)
        *(uint4v*)(top_in + (size_t)b*KP4 + r*64 + h*8 + p*16) = q[p];
    }
    f32x16 acc;
    #pragma unroll
    for(int i = 0; i < 16; i++) acc[i] = 0.f;
    #pragma unroll
    for(int p = 0; p < 4; p++){
      bf16x8 a = __builtin_bit_cast(bf16x8, q[p]);
      acc = __builtin_amdgcn_mfma_f32_32x32x16_bf16(a, a, acc, 0, 0, 0);
    }
    if(r < NEMB){
      #pragma unroll
      for(int qq = 0; qq < 16; qq++){
        int i = (qq & 3) + 8*(qq >> 2) + 4*h;
        if(i < r){
          int p = i*(53 - i)/2 + (r - i - 1);
          inter_s[sb][p] = (unsigned short)f2bf(acc[qq]);
        }
      }
    }
    asm volatile("s_waitcnt lgkmcnt(0)" ::: "memory");   // wave-local LDS visibility
    size_t basei = (size_t)b*KP4 + 1728;
    for(int t0 = l; t0 < 176; t0 += 64){
      uint32_t lo = inter_s[sb][2*t0];
      uint32_t hi = (2*t0 + 1 < NINTER) ? (uint32_t)inter_s[sb][2*t0 + 1] : 0u;
      *(uint32_t*)(top_in + basei + 2*t0) = lo | (hi << 16);
    }
    if(l < 16) *(uint32_t*)(top_in + (size_t)b*KP4 + 2080 + 2*l) = 0;
  }
}

// ---------------- gemm4: 256x128, 8 waves, triple-buffer, 2-phase, 16x16 ------
template<int KSTEPS, int NB>
__global__ __launch_bounds__(512, 2) void gemm_deep(
    const unsigned short* __restrict__ A, int sA,
    const unsigned short* __restrict__ Bw, int sB,
    const float* __restrict__ bias, const float* __restrict__ gg,
    const float* __restrict__ be,
    unsigned short* __restrict__ out, int sOut){
  __shared__ char smem[3*49152];          // 3 bufs: A 32KB + B 16KB each
  int nwg = gridDim.x;
  int bid = blockIdx.x;
  int lin = (bid & 7) * (nwg >> 3) + (bid >> 3);   // XCD chunking (nwg % 8 == 0)
  int m0 = (lin / NB) * 256, n0 = (lin % NB) * 128;
  int t = threadIdx.x, w = t >> 6, l = t & 63;
  int wr = (w >> 1) * 64, wc = (w & 1) * 64;
  f32x4 acc[4][4];
  #pragma unroll
  for(int i = 0; i < 4; i++)
    #pragma unroll
    for(int j = 0; j < 4; j++)
      #pragma unroll
      for(int e = 0; e < 4; e++) acc[i][j][e] = 0.f;

  const unsigned short* g[6];
  int ldsOff[6];
  #pragma unroll
  for(int i = 0; i < 6; i++){
    if(i < 4){
      int o = i*8192 + t*16;
      int row = o >> 7;
      int cb  = (o & 127) ^ ((row & 7) << 4);
      g[i] = A + (size_t)(m0 + row)*sA + (cb >> 1);
      ldsOff[i] = o;
    } else {
      int o = (i-4)*8192 + t*16;
      int row = o >> 7;
      int cb  = (o & 127) ^ ((row & 7) << 4);
      g[i] = Bw + (size_t)(n0 + row)*sB + (cb >> 1);
      ldsOff[i] = 32768 + o;
    }
  }
  int lr = l & 15;
  int o1 = ((l >> 4) * 16) ^ ((l & 7) << 4);

  // prologue: stage K-tiles 0 and 1
  #pragma unroll
  for(int i = 0; i < 6; i++) async_load16(g[i], smem + ldsOff[i]);
  #pragma unroll
  for(int i = 0; i < 6; i++) async_load16(g[i] + 64, smem + 49152 + ldsOff[i]);
  asm volatile("s_waitcnt vmcnt(6)" ::: "memory");
  __builtin_amdgcn_s_barrier();

  for(int kt = 0; kt < KSTEPS; kt++){
    int cur = kt % 3;
    int nxt2 = (kt + 2) % 3;
    int ksrc = (kt + 2 < KSTEPS) ? (kt + 2) : (KSTEPS - 1);  // clamped dup, never read
    const char* bA = smem + cur*49152;
    const char* bB = bA + 32768;
    // ---- phase 0 (ks = 0) ----
    #pragma unroll
    for(int i = 0; i < 3; i++)
      async_load16(g[i] + ksrc*64, smem + nxt2*49152 + ldsOff[i]);
    {
      bf16x8 af[4], bfr[4];
      #pragma unroll
      for(int x = 0; x < 4; x++){
        af[x]  = *(const bf16x8*)(bA + (wr + x*16 + lr)*128 + o1);
        bfr[x] = *(const bf16x8*)(bB + (wc + x*16 + lr)*128 + o1);
      }
      __builtin_amdgcn_s_barrier();
      __builtin_amdgcn_s_setprio(1);
      #pragma unroll
      for(int tr = 0; tr < 4; tr++)
        #pragma unroll
        for(int tc = 0; tc < 4; tc++)
          acc[tr][tc] = __builtin_amdgcn_mfma_f32_16x16x32_bf16(af[tr], bfr[tc], acc[tr][tc], 0, 0, 0);
      __builtin_amdgcn_s_setprio(0);
    }
    __builtin_amdgcn_s_barrier();
    // ---- phase 1 (ks = 1) ----
    #pragma unroll
    for(int i = 3; i < 6; i++)
      async_load16(g[i] + ksrc*64, smem + nxt2*49152 + ldsOff[i]);
    {
      bf16x8 af[4], bfr[4];
      int ko = o1 ^ 64;
      #pragma unroll
      for(int x = 0; x < 4; x++){
        af[x]  = *(const bf16x8*)(bA + (wr + x*16 + lr)*128 + ko);
        bfr[x] = *(const bf16x8*)(bB + (wc + x*16 + lr)*128 + ko);
      }
      asm volatile("s_waitcnt vmcnt(6)" ::: "memory");   // kt+1 landed; kt+2 in flight
      __builtin_amdgcn_s_barrier();
      __builtin_amdgcn_s_setprio(1);
      #pragma unroll
      for(int tr = 0; tr < 4; tr++)
        #pragma unroll
        for(int tc = 0; tc < 4; tc++)
          acc[tr][tc] = __builtin_amdgcn_mfma_f32_16x16x32_bf16(af[tr], bfr[tc], acc[tr][tc], 0, 0, 0);
      __builtin_amdgcn_s_setprio(0);
    }
    __builtin_amdgcn_s_barrier();
  }

  #pragma unroll
  for(int tc = 0; tc < 4; tc++){
    int n = n0 + wc + tc*16 + lr;
    float sc = gg[n]*BN_INVF, bo = be[n], bi = bias[n];
    #pragma unroll
    for(int tr = 0; tr < 4; tr++){
      int mb = m0 + wr + tr*16 + (l >> 4)*4;
      #pragma unroll
      for(int qq = 0; qq < 4; qq++){
        float y = fmaxf(sc*(acc[tr][tc][qq] + bi) + bo, 0.f);
        out[(size_t)(mb + qq)*sOut + n] = (unsigned short)f2bf(y);
      }
    }
  }
}

// ---------------- gemm_tail: layers 5+6+7 fused, 64 rows/block, 4 waves -------
__global__ __launch_bounds__(256) void gemm_tail(
    const unsigned short* __restrict__ h4,      // [BATCH][512]
    const unsigned short* __restrict__ W5t,     // [256][512]
    const float* __restrict__ b5, const float* __restrict__ g5, const float* __restrict__ be5,
    const unsigned short* __restrict__ W6t,     // [128][256]
    const float* __restrict__ b6, const float* __restrict__ g6, const float* __restrict__ be6,
    const float* __restrict__ W7, const float* __restrict__ b7,
    float* __restrict__ scores){
  __shared__ char smem[74752];
  unsigned short* h5 = (unsigned short*)(smem + 40960);
  float* pscore = (float*)(smem + 73728);
  int t = threadIdx.x, w = t >> 6, l = t & 63;
  int m0 = blockIdx.x * 64;
  int lr = l & 15;
  int o1 = ((l >> 4) * 16) ^ ((l & 7) << 4);

  f32x4 acc5[4][4];
  #pragma unroll
  for(int i = 0; i < 4; i++)
    #pragma unroll
    for(int j = 0; j < 4; j++)
      #pragma unroll
      for(int e = 0; e < 4; e++) acc5[i][j][e] = 0.f;

  const unsigned short* gA[2]; int ldsA[2];
  #pragma unroll
  for(int i = 0; i < 2; i++){
    int o = i*4096 + t*16;
    int row = o >> 7;
    int cb = (o & 127) ^ ((row & 7) << 4);
    gA[i] = h4 + (size_t)(m0 + row)*512 + (cb >> 1);
    ldsA[i] = o;
  }
  const unsigned short* gB[8]; int ldsB[8];
  #pragma unroll
  for(int i = 0; i < 8; i++){
    int o = i*4096 + t*16;
    int row = o >> 7;
    int cb = (o & 127) ^ ((row & 7) << 4);
    gB[i] = W5t + (size_t)row*512 + (cb >> 1);
    ldsB[i] = 8192 + o;
  }

  for(int kt = 0; kt < 8; kt++){
    #pragma unroll
    for(int i = 0; i < 2; i++) async_load16(gA[i] + kt*64, smem + ldsA[i]);
    #pragma unroll
    for(int i = 0; i < 8; i++) async_load16(gB[i] + kt*64, smem + ldsB[i]);
    __syncthreads();
    #pragma unroll
    for(int ks = 0; ks < 2; ks++){
      int ko = o1 ^ (ks << 6);
      bf16x8 af[4], bfr[4];
      #pragma unroll
      for(int x = 0; x < 4; x++){
        af[x]  = *(const bf16x8*)(smem + (x*16 + lr)*128 + ko);
        bfr[x] = *(const bf16x8*)(smem + 8192 + (w*64 + x*16 + lr)*128 + ko);
      }
      #pragma unroll
      for(int tr = 0; tr < 4; tr++)
        #pragma unroll
        for(int tc = 0; tc < 4; tc++)
          acc5[tr][tc] = __builtin_amdgcn_mfma_f32_16x16x32_bf16(af[tr], bfr[tc], acc5[tr][tc], 0, 0, 0);
    }
    __syncthreads();
  }

  #pragma unroll
  for(int i = 0; i < 8; i++){
    int o = i*4096 + t*16;
    int row = o >> 8;
    int cb = (o & 255) ^ ((row & 15) << 4);
    async_load16(W6t + (size_t)row*256 + (cb >> 1), smem + o);
  }
  #pragma unroll
  for(int tc = 0; tc < 4; tc++){
    int c = w*64 + tc*16 + lr;
    float sc = g5[c]*BN_INVF, bo = be5[c], bi = b5[c];
    #pragma unroll
    for(int tr = 0; tr < 4; tr++){
      #pragma unroll
      for(int qq = 0; qq < 4; qq++){
        int row = tr*16 + (l >> 4)*4 + qq;
        float y = fmaxf(sc*(acc5[tr][tc][qq] + bi) + bo, 0.f);
        h5[row*256 + (c ^ rswz(row))] = (unsigned short)f2bf(y);
      }
    }
  }
  __syncthreads();

  f32x4 acc6[4][2];
  #pragma unroll
  for(int i = 0; i < 4; i++)
    #pragma unroll
    for(int j = 0; j < 2; j++)
      #pragma unroll
      for(int e = 0; e < 4; e++) acc6[i][j][e] = 0.f;
  int lk = (l >> 4) * 8;
  int lk2 = (l >> 4) * 16;
  #pragma unroll
  for(int half = 0; half < 2; half++){
    if(half == 1){
      __syncthreads();
      #pragma unroll
      for(int i = 0; i < 8; i++){
        int o = i*4096 + t*16;
        int row = o >> 8;
        int cb = (o & 255) ^ ((row & 15) << 4);
        async_load16(W6t + (size_t)row*256 + 128 + (cb >> 1), smem + o);
      }
      __syncthreads();
    }
    #pragma unroll
    for(int ks = 0; ks < 4; ks++){
      bf16x8 af6[4], bfr6[2];
      #pragma unroll
      for(int mt = 0; mt < 4; mt++){
        int row = mt*16 + lr;
        af6[mt] = *(const bf16x8*)(h5 + row*256 + ((half*128 + ks*32 + lk) ^ rswz(row)));
      }
      #pragma unroll
      for(int nt = 0; nt < 2; nt++){
        int row = w*32 + nt*16 + lr;
        bfr6[nt] = *(const bf16x8*)(smem + row*256 + ((ks*64 + lk2) ^ (lr << 4)));
      }
      #pragma unroll
      for(int mt = 0; mt < 4; mt++)
        #pragma unroll
        for(int nt = 0; nt < 2; nt++)
          acc6[mt][nt] = __builtin_amdgcn_mfma_f32_16x16x32_bf16(af6[mt], bfr6[nt], acc6[mt][nt], 0, 0, 0);
    }
  }

  float pr[16];
  #pragma unroll
  for(int nt = 0; nt < 2; nt++){
    int c = w*32 + nt*16 + lr;
    float sc = g6[c]*BN_INVF, bo = be6[c], bi = b6[c];
    float w7c = W7[c];
    #pragma unroll
    for(int mt = 0; mt < 4; mt++){
      #pragma unroll
      for(int qq = 0; qq < 4; qq++){
        float v = fmaxf(sc*(acc6[mt][nt][qq] + bi) + bo, 0.f) * w7c;
        if(nt == 0) pr[mt*4 + qq] = v; else pr[mt*4 + qq] += v;
      }
    }
  }
  #pragma unroll
  for(int mask = 1; mask < 16; mask <<= 1){
    #pragma unroll
    for(int i = 0; i < 16; i++) pr[i] += __shfl_xor(pr[i], mask, 64);
  }
  if(lr == 0){
    #pragma unroll
    for(int mt = 0; mt < 4; mt++)
      #pragma unroll
      for(int qq = 0; qq < 4; qq++)
        pscore[w*64 + mt*16 + (l >> 4)*4 + qq] = pr[mt*4 + qq];
  }
  __syncthreads();
  if(t < 64){
    float s = b7[0] + pscore[t] + pscore[64 + t] + pscore[128 + t] + pscore[192 + t];
    scores[m0 + t] = s;
  }
}

// ---------------- launch ----------------
static inline size_t alignup(size_t x){ return (x + 255) & ~(size_t)255; }

extern "C" void kernel_launch(void* const* d_in, const int* in_sizes, int n_in,
                              void* d_out, int out_size, void* d_ws, size_t ws_size,
                              hipStream_t stream){
  const float* cont = (const float*)d_in[0];
  const int*   cat  = (const int*)  d_in[1];
  const float* emb  = (const float*)d_in[2];
  const float* W1 = (const float*)d_in[3],  *b1 = (const float*)d_in[4];
  const float* g1 = (const float*)d_in[5],  *be1= (const float*)d_in[6];
  const float* W2 = (const float*)d_in[7],  *b2 = (const float*)d_in[8];
  const float* g2 = (const float*)d_in[9],  *be2= (const float*)d_in[10];
  const float* W3 = (const float*)d_in[11], *b3 = (const float*)d_in[12];
  const float* W4 = (const float*)d_in[13], *b4 = (const float*)d_in[14];
  const float* g4 = (const float*)d_in[15], *be4= (const float*)d_in[16];
  const float* W5 = (const float*)d_in[17], *b5 = (const float*)d_in[18];
  const float* g5 = (const float*)d_in[19], *be5= (const float*)d_in[20];
  const float* W6 = (const float*)d_in[21], *b6 = (const float*)d_in[22];
  const float* g6 = (const float*)d_in[23], *be6= (const float*)d_in[24];
  const float* W7 = (const float*)d_in[25], *b7 = (const float*)d_in[26];

  char* ws = (char*)d_ws;
  unsigned short* W1t  = (unsigned short*)ws; ws += alignup((size_t)256*32*2);
  unsigned short* W2t  = (unsigned short*)ws; ws += alignup((size_t)128*256*2);
  unsigned short* W3t  = (unsigned short*)ws; ws += alignup((size_t)64*128*2);
  unsigned short* topi = (unsigned short*)ws; ws += alignup((size_t)BATCH*KP4*2);
  unsigned short* W4t  = (unsigned short*)ws; ws += alignup((size_t)512*KP4*2);
  unsigned short* W5t  = (unsigned short*)ws; ws += alignup((size_t)256*512*2);
  unsigned short* W6t  = (unsigned short*)ws; ws += alignup((size_t)128*256*2);
  unsigned short* h4   = (unsigned short*)ws; ws += alignup((size_t)BATCH*512*2);
  (void)ws_size; (void)n_in; (void)in_sizes; (void)out_size;

  hipLaunchKernelGGL(prep, dim3(318), dim3(256), 0, stream,
                     W1, W2, W3, W4, W5, W6,
                     W1t, W2t, W3t, W4t, W5t, W6t);
  hipLaunchKernelGGL(bottom_interact, dim3(BATCH/16), dim3(256), 0, stream,
                     cont, cat, emb, W1t, W2t, W3t,
                     b1, g1, be1, b2, g2, be2, b3, topi);
  hipLaunchKernelGGL((gemm_deep<33, 4>), dim3(256), dim3(512), 0, stream,
                     topi, KP4, W4t, KP4, b4, g4, be4, h4, 512);
  hipLaunchKernelGGL(gemm_tail, dim3(256), dim3(256), 0, stream,
                     h4, W5t, b5, g5, be5, W6t, b6, g6, be6, W7, b7, (float*)d_out);
}